// Round 1
// baseline (2410.503 us; speedup 1.0000x reference)
//
#include <hip/hip_runtime.h>
#include <hip/hip_bf16.h>
#include <math.h>

#define B_   64
#define S_   512
#define K_   16
#define DU_  64
#define DI_  192
#define H_   256
#define H4_  1024

// ---------------- reduction helpers ----------------
__device__ __forceinline__ float wave_reduce_sum(float v) {
#pragma unroll
  for (int off = 32; off; off >>= 1) v += __shfl_down(v, off, 64);
  return v;
}
__device__ __forceinline__ float wave_reduce_max(float v) {
#pragma unroll
  for (int off = 32; off; off >>= 1) v = fmaxf(v, __shfl_down(v, off, 64));
  return v;
}

// ---------------- gather: x = [embed_item[cand], embed_user[user]] ----------------
__global__ void gather_x(const int* __restrict__ users, const int* __restrict__ cand,
                         const float* __restrict__ eu, const float* __restrict__ ei,
                         float* __restrict__ x)
{
  int idx = blockIdx.x * 256 + threadIdx.x;          // B*S*H = 8388608
  int h  = idx & (H_ - 1);
  int bs = idx >> 8;                                  // b*S + s
  int b  = bs >> 9;
  float v;
  if (h < DI_) v = ei[(long)cand[bs] * DI_ + h];
  else         v = eu[(long)users[b] * DU_ + (h - DI_)];
  x[idx] = v;
}

// ---------------- tiled fp32 GEMM:  C = A @ B (+bias) (+relu), NT => C = A @ B^T ----------------
#define BM 64
#define BN 64
#define BK 16

template<bool NT, bool RELU>
__global__ __launch_bounds__(256) void gemm_kernel(
    const float* __restrict__ A, const float* __restrict__ Bm,
    const float* __restrict__ bias, float* __restrict__ C,
    int M, int N, int Kd, int ldA, int ldB, int ldC,
    long sA, long sB, long sC)
{
  __shared__ float As[BK][BM + 4];
  __shared__ float Bs[BK][BN + 4];
  const int bx = blockIdx.x, by = blockIdx.y, bz = blockIdx.z;
  A  += (long)bz * sA;
  Bm += (long)bz * sB;
  C  += (long)bz * sC;
  const int tid = threadIdx.x;
  const int tx = tid & 15, ty = tid >> 4;
  float acc[4][4] = {};

  const int arow  = tid >> 2;            // 0..63
  const int acol4 = (tid & 3) * 4;       // 0,4,8,12

  for (int k0 = 0; k0 < Kd; k0 += BK) {
    // A tile: 64 x 16
    {
      const float4 av = *(const float4*)(A + (long)(by * BM + arow) * ldA + k0 + acol4);
      As[acol4 + 0][arow] = av.x; As[acol4 + 1][arow] = av.y;
      As[acol4 + 2][arow] = av.z; As[acol4 + 3][arow] = av.w;
    }
    if (!NT) {
      const int brow = tid >> 4, bcol4 = (tid & 15) * 4;
      const float4 bv = *(const float4*)(Bm + (long)(k0 + brow) * ldB + bx * BN + bcol4);
      Bs[brow][bcol4 + 0] = bv.x; Bs[brow][bcol4 + 1] = bv.y;
      Bs[brow][bcol4 + 2] = bv.z; Bs[brow][bcol4 + 3] = bv.w;
    } else {
      const int bn = tid >> 2, bk4 = (tid & 3) * 4;
      const float4 bv = *(const float4*)(Bm + (long)(bx * BN + bn) * ldB + k0 + bk4);
      Bs[bk4 + 0][bn] = bv.x; Bs[bk4 + 1][bn] = bv.y;
      Bs[bk4 + 2][bn] = bv.z; Bs[bk4 + 3][bn] = bv.w;
    }
    __syncthreads();
#pragma unroll
    for (int kk = 0; kk < BK; ++kk) {
      float a0 = As[kk][ty * 4 + 0], a1 = As[kk][ty * 4 + 1];
      float a2 = As[kk][ty * 4 + 2], a3 = As[kk][ty * 4 + 3];
      float b0 = Bs[kk][tx * 4 + 0], b1 = Bs[kk][tx * 4 + 1];
      float b2 = Bs[kk][tx * 4 + 2], b3 = Bs[kk][tx * 4 + 3];
      acc[0][0] += a0 * b0; acc[0][1] += a0 * b1; acc[0][2] += a0 * b2; acc[0][3] += a0 * b3;
      acc[1][0] += a1 * b0; acc[1][1] += a1 * b1; acc[1][2] += a1 * b2; acc[1][3] += a1 * b3;
      acc[2][0] += a2 * b0; acc[2][1] += a2 * b1; acc[2][2] += a2 * b2; acc[2][3] += a2 * b3;
      acc[3][0] += a3 * b0; acc[3][1] += a3 * b1; acc[3][2] += a3 * b2; acc[3][3] += a3 * b3;
    }
    __syncthreads();
  }

  const int col4 = bx * BN + tx * 4;
  float4 bias4 = make_float4(0.f, 0.f, 0.f, 0.f);
  if (bias) bias4 = *(const float4*)(bias + col4);
#pragma unroll
  for (int i = 0; i < 4; ++i) {
    const int row = by * BM + ty * 4 + i;
    float4 o;
    o.x = acc[i][0] + bias4.x; o.y = acc[i][1] + bias4.y;
    o.z = acc[i][2] + bias4.z; o.w = acc[i][3] + bias4.w;
    if (RELU) {
      o.x = fmaxf(o.x, 0.f); o.y = fmaxf(o.y, 0.f);
      o.z = fmaxf(o.z, 0.f); o.w = fmaxf(o.w, 0.f);
    }
    *(float4*)(C + (long)row * ldC + col4) = o;
  }
}

// ---------------- attention softmax (rows of length 512, scaled by 1/16) ----------------
__global__ __launch_bounds__(256) void attn_softmax(float* __restrict__ att)
{
  __shared__ float red[8];
  const long row = blockIdx.x;
  float* p = att + row * S_;
  const int t = threadIdx.x, lane = t & 63, wid = t >> 6;
  float v0 = p[t] * 0.0625f, v1 = p[t + 256] * 0.0625f;
  float m = wave_reduce_max(fmaxf(v0, v1));
  if (!lane) red[wid] = m;
  __syncthreads();
  const float bm = fmaxf(fmaxf(red[0], red[1]), fmaxf(red[2], red[3]));
  const float e0 = __expf(v0 - bm), e1 = __expf(v1 - bm);
  float s = wave_reduce_sum(e0 + e1);
  __syncthreads();
  if (!lane) red[wid] = s;
  __syncthreads();
  const float inv = 1.f / (red[0] + red[1] + red[2] + red[3]);
  p[t] = e0 * inv; p[t + 256] = e1 * inv;
}

// ---------------- residual + layernorm (in-place into x) ----------------
__global__ __launch_bounds__(256) void ln_res(float* __restrict__ x, const float* __restrict__ y,
                                              const float* __restrict__ g, const float* __restrict__ b)
{
  __shared__ float red[8];
  const long row = blockIdx.x;
  const int t = threadIdx.x, lane = t & 63, wid = t >> 6;
  float v = x[row * H_ + t] + y[row * H_ + t];
  float s = wave_reduce_sum(v);
  if (!lane) red[wid] = s;
  __syncthreads();
  const float mean = (red[0] + red[1] + red[2] + red[3]) * (1.f / H_);
  const float d = v - mean;
  float s2 = wave_reduce_sum(d * d);
  __syncthreads();
  if (!lane) red[wid] = s2;
  __syncthreads();
  const float var = (red[0] + red[1] + red[2] + red[3]) * (1.f / H_);
  x[row * H_ + t] = d * rsqrtf(var + 1e-5f) * g[t] + b[t];
}

// ---------------- gather LSTM inputs (K,B,H), step 0 zeroed ----------------
__global__ void gather_inputs(const int* __restrict__ tidx, const float* __restrict__ enc,
                              float* __restrict__ inp)
{
  int idx = blockIdx.x * 256 + threadIdx.x;          // K*B*H = 262144
  int h = idx & 255, kb = idx >> 8;
  int b = kb & 63, k = kb >> 6;
  float v = 0.f;
  if (k > 0) {
    int s = tidx[b * K_ + k];
    v = enc[((long)b * S_ + s) * H_ + h];
  }
  inp[idx] = v;
}

// ---------------- transpose W_hh (4H x H) -> (H x 4H) ----------------
__global__ void transpose_whh(const float* __restrict__ W, float* __restrict__ WT)
{
  int idx = blockIdx.x * 256 + threadIdx.x;          // 262144
  int r = idx >> 8, d = idx & 255;
  WT[d * H4_ + r] = W[idx];
}

// ---------------- one LSTM step; dec holds packed (h,c) per step ----------------
__global__ __launch_bounds__(256) void lstm_step(const float* __restrict__ Xp,
                                                 const float* __restrict__ WhhT,
                                                 const float* __restrict__ b_hh,
                                                 float* __restrict__ dec, int step)
{
  __shared__ float hs[H_];
  const int b = blockIdx.x, t = threadIdx.x;
  float hprev = 0.f, cprev = 0.f;
  if (step > 0) {
    const long pr = ((long)(step - 1) * B_ + b) * (2 * H_);
    hprev = dec[pr + t];
    cprev = dec[pr + H_ + t];
  }
  hs[t] = hprev;
  __syncthreads();
  const long rowX = ((long)step * B_ + b) * H4_;
  float gi = Xp[rowX + t]       + b_hh[t];
  float gf = Xp[rowX + 256 + t] + b_hh[256 + t];
  float gg = Xp[rowX + 512 + t] + b_hh[512 + t];
  float go = Xp[rowX + 768 + t] + b_hh[768 + t];
  for (int d = 0; d < H_; ++d) {
    const float hd = hs[d];
    const float* wr = WhhT + d * H4_;
    gi += hd * wr[t];
    gf += hd * wr[256 + t];
    gg += hd * wr[512 + t];
    go += hd * wr[768 + t];
  }
  const float i_ = 1.f / (1.f + __expf(-gi));
  const float f_ = 1.f / (1.f + __expf(-gf));
  const float g_ = tanhf(gg);
  const float o_ = 1.f / (1.f + __expf(-go));
  const float c = f_ * cprev + i_ * g_;
  const float h = o_ * tanhf(c);
  const long rw = ((long)step * B_ + b) * (2 * H_);
  dec[rw + t] = h;
  dec[rw + H_ + t] = c;
}

// ---------------- glimpse: scores -> softmax(S) -> weighted sum of enc ----------------
__global__ __launch_bounds__(256) void glimpse_kernel(
    const float* __restrict__ decW1, const float* __restrict__ encW2,
    const float* __restrict__ enc, const float* __restrict__ bias1,
    const float* __restrict__ V1, float* __restrict__ glim)
{
  __shared__ float dv[H_], vd[H_], sc[S_], red[8];
  const int bid = blockIdx.x;                // k*B + b
  const int b = bid & 63;
  const int t = threadIdx.x, lane = t & 63, wave = t >> 6;
  dv[t] = decW1[(long)bid * H_ + t] + bias1[t];
  vd[t] = V1[t];
  __syncthreads();
  for (int s = wave; s < S_; s += 4) {
    const float* er = encW2 + ((long)b * S_ + s) * H_;
    float val = 0.f;
#pragma unroll
    for (int hh = 0; hh < 4; ++hh) {
      const int h = hh * 64 + lane;
      val += tanhf(dv[h] + er[h]) * vd[h];
    }
    val = wave_reduce_sum(val);
    if (lane == 0) sc[s] = val;
  }
  __syncthreads();
  // softmax over sc[0..511]
  float v0 = sc[t], v1 = sc[t + 256];
  float m = wave_reduce_max(fmaxf(v0, v1));
  if (!lane) red[wave] = m;
  __syncthreads();
  const float bm = fmaxf(fmaxf(red[0], red[1]), fmaxf(red[2], red[3]));
  const float e0 = __expf(v0 - bm), e1 = __expf(v1 - bm);
  float ssum = wave_reduce_sum(e0 + e1);
  __syncthreads();
  if (!lane) red[wave] = ssum;
  __syncthreads();
  const float inv = 1.f / (red[0] + red[1] + red[2] + red[3]);
  sc[t] = e0 * inv; sc[t + 256] = e1 * inv;
  __syncthreads();
  float acc = 0.f;
  const float* eb = enc + (long)b * S_ * H_ + t;
  for (int s = 0; s < S_; ++s) acc += sc[s] * eb[(long)s * H_];
  glim[(long)bid * H_ + t] = acc;
}

// ---------------- gcat = [dec | glim] ----------------
__global__ void concat_gcat(const float* __restrict__ dec, const float* __restrict__ glim,
                            float* __restrict__ gcat)
{
  int idx = blockIdx.x * 256 + threadIdx.x;   // 1024*768
  int j = idx % 768, row = idx / 768;
  gcat[idx] = (j < 512) ? dec[(long)row * 512 + j] : glim[(long)row * 256 + (j - 512)];
}

// ---------------- pointer logits -> out[b,k,s] ----------------
__global__ __launch_bounds__(256) void pointer_kernel(
    const float* __restrict__ gW3, const float* __restrict__ encW4,
    const float* __restrict__ bias2, const float* __restrict__ V2,
    float* __restrict__ out)
{
  __shared__ float dv[H_], vd[H_], sc[S_];
  const int bid = blockIdx.x;                // k*B + b
  const int b = bid & 63, k = bid >> 6;
  const int t = threadIdx.x, lane = t & 63, wave = t >> 6;
  dv[t] = gW3[(long)bid * H_ + t] + bias2[t];
  vd[t] = V2[t];
  __syncthreads();
  for (int s = wave; s < S_; s += 4) {
    const float* er = encW4 + ((long)b * S_ + s) * H_;
    float val = 0.f;
#pragma unroll
    for (int hh = 0; hh < 4; ++hh) {
      const int h = hh * 64 + lane;
      val += tanhf(dv[h] + er[h]) * vd[h];
    }
    val = wave_reduce_sum(val);
    if (lane == 0) sc[s] = val;
  }
  __syncthreads();
  const long ro = ((long)b * K_ + k) * S_;
  out[ro + t] = sc[t];
  out[ro + 256 + t] = sc[t + 256];
}

// ---------------- host ----------------
extern "C" void kernel_launch(void* const* d_in, const int* in_sizes, int n_in,
                              void* d_out, int out_size, void* d_ws, size_t ws_size,
                              hipStream_t stream)
{
  const int*   users = (const int*)d_in[0];
  const int*   cand  = (const int*)d_in[1];
  const int*   tidx  = (const int*)d_in[2];
  const float* eu    = (const float*)d_in[3];
  const float* ei    = (const float*)d_in[4];
  const float* Wq    = (const float*)d_in[5];
  const float* bq    = (const float*)d_in[6];
  const float* Wk    = (const float*)d_in[7];
  const float* bk    = (const float*)d_in[8];
  const float* Wv    = (const float*)d_in[9];
  const float* bv    = (const float*)d_in[10];
  const float* Wo    = (const float*)d_in[11];
  const float* bo    = (const float*)d_in[12];
  const float* ln1g  = (const float*)d_in[13];
  const float* ln1b  = (const float*)d_in[14];
  const float* Wf1   = (const float*)d_in[15];
  const float* bf1   = (const float*)d_in[16];
  const float* Wf2   = (const float*)d_in[17];
  const float* bf2   = (const float*)d_in[18];
  const float* ln2g  = (const float*)d_in[19];
  const float* ln2b  = (const float*)d_in[20];
  const float* W_ih  = (const float*)d_in[21];
  const float* W_hh  = (const float*)d_in[22];
  const float* b_ih  = (const float*)d_in[23];
  const float* b_hh  = (const float*)d_in[24];
  const float* W_D1  = (const float*)d_in[25];
  const float* W_D2  = (const float*)d_in[26];
  const float* bias1 = (const float*)d_in[27];
  const float* V_D1  = (const float*)d_in[28];
  const float* W_D3  = (const float*)d_in[29];
  const float* W_D4  = (const float*)d_in[30];
  const float* bias2 = (const float*)d_in[31];
  const float* V_D2  = (const float*)d_in[32];

  float* ws = (float*)d_ws;
  const long NROW = (long)B_ * S_;            // 32768
  const long XSZ  = NROW * H_;                // 8388608 floats
  float* x    = ws;                            // enc lives here at the end
  float* qb   = x  + XSZ;                      // later: y (Wo out), encW2
  float* kb   = qb + XSZ;                      // later: mid chunk, encW4
  float* vb   = kb + XSZ;                      // later: small arena
  float* ao   = vb + XSZ;                      // attention output
  float* attc = ao + XSZ;                      // 4194304 floats: att chunk / y2 chunk
  // small arena (inside vb, used after attention phase)
  float* inp    = vb;                          // 262144
  float* Xp     = inp  + 262144;               // 1048576
  float* WhhT   = Xp   + 1048576;              // 262144
  float* dec    = WhhT + 262144;               // 524288
  float* decW1  = dec  + 524288;               // 262144
  float* glim   = decW1 + 262144;              // 262144
  float* gcat   = glim + 262144;               // 786432
  float* gcatW3 = gcat + 786432;               // 262144

  float* out = (float*)d_out;

  // 1. gather x
  gather_x<<<dim3(32768), dim3(256), 0, stream>>>(users, cand, eu, ei, x);

  // 2. q,k,v projections
  gemm_kernel<false,false><<<dim3(4,512), dim3(256), 0, stream>>>(x, Wq, bq, qb, 32768, H_, H_, H_, H_, H_, 0,0,0);
  gemm_kernel<false,false><<<dim3(4,512), dim3(256), 0, stream>>>(x, Wk, bk, kb, 32768, H_, H_, H_, H_, H_, 0,0,0);
  gemm_kernel<false,false><<<dim3(4,512), dim3(256), 0, stream>>>(x, Wv, bv, vb, 32768, H_, H_, H_, H_, H_, 0,0,0);

  // 3. attention, 4 chunks of 16 batches
  for (int c = 0; c < 4; ++c) {
    const long qoff = (long)c * 16 * S_ * H_;
    gemm_kernel<true,false><<<dim3(8,8,16), dim3(256), 0, stream>>>(
        qb + qoff, kb + qoff, nullptr, attc, S_, S_, H_, H_, H_, S_,
        (long)S_*H_, (long)S_*H_, (long)S_*S_);
    attn_softmax<<<dim3(16*S_), dim3(256), 0, stream>>>(attc);
    gemm_kernel<false,false><<<dim3(4,8,16), dim3(256), 0, stream>>>(
        attc, vb + qoff, nullptr, ao + qoff, S_, H_, S_, S_, H_, H_,
        (long)S_*S_, (long)S_*H_, (long)S_*H_);
  }

  // 4. Wo projection + residual LN1 (y into qb region)
  gemm_kernel<false,false><<<dim3(4,512), dim3(256), 0, stream>>>(ao, Wo, bo, qb, 32768, H_, H_, H_, H_, H_, 0,0,0);
  ln_res<<<dim3(32768), dim3(256), 0, stream>>>(x, qb, ln1g, ln1b);

  // 5. FFN, 4 chunks of 8192 rows (mid in kb, y2 in attc)
  for (int c = 0; c < 4; ++c) {
    float* xc = x + (long)c * 8192 * H_;
    gemm_kernel<false,true ><<<dim3(16,128), dim3(256), 0, stream>>>(xc, Wf1, bf1, kb, 8192, H4_, H_, H_, H4_, H4_, 0,0,0);
    gemm_kernel<false,false><<<dim3(4,128), dim3(256), 0, stream>>>(kb, Wf2, bf2, attc, 8192, H_, H4_, H4_, H_, H_, 0,0,0);
    ln_res<<<dim3(8192), dim3(256), 0, stream>>>(xc, attc, ln2g, ln2b);
  }
  // x now holds enc

  // 6. enc @ W_D2 -> qb, enc @ W_D4 -> kb
  gemm_kernel<false,false><<<dim3(4,512), dim3(256), 0, stream>>>(x, W_D2, nullptr, qb, 32768, H_, H_, H_, H_, H_, 0,0,0);
  gemm_kernel<false,false><<<dim3(4,512), dim3(256), 0, stream>>>(x, W_D4, nullptr, kb, 32768, H_, H_, H_, H_, H_, 0,0,0);

  // 7. LSTM
  gather_inputs<<<dim3(1024), dim3(256), 0, stream>>>(tidx, x, inp);
  gemm_kernel<true,false><<<dim3(16,16), dim3(256), 0, stream>>>(inp, W_ih, b_ih, Xp, K_*B_, H4_, H_, H_, H_, H4_, 0,0,0);
  transpose_whh<<<dim3(1024), dim3(256), 0, stream>>>(W_hh, WhhT);
  for (int step = 0; step < K_; ++step)
    lstm_step<<<dim3(B_), dim3(256), 0, stream>>>(Xp, WhhT, b_hh, dec, step);

  // 8. glimpse
  gemm_kernel<false,false><<<dim3(4,16), dim3(256), 0, stream>>>(dec, W_D1, nullptr, decW1, K_*B_, H_, 2*H_, 2*H_, H_, H_, 0,0,0);
  glimpse_kernel<<<dim3(K_*B_), dim3(256), 0, stream>>>(decW1, qb, x, bias1, V_D1, glim);

  // 9. pointer
  concat_gcat<<<dim3(3072), dim3(256), 0, stream>>>(dec, glim, gcat);
  gemm_kernel<false,false><<<dim3(4,16), dim3(256), 0, stream>>>(gcat, W_D3, nullptr, gcatW3, K_*B_, H_, 3*H_, 3*H_, H_, H_, 0,0,0);
  pointer_kernel<<<dim3(K_*B_), dim3(256), 0, stream>>>(gcatW3, kb, bias2, V_D2, out);
}

// Round 3
// 2400.169 us; speedup vs baseline: 1.0043x; 1.0043x over previous
//
#include <hip/hip_runtime.h>
#include <hip/hip_bf16.h>
#include <math.h>

#define B_   64
#define S_   512
#define K_   16
#define DU_  64
#define DI_  192
#define H_   256
#define H4_  1024

// ---------------- helpers ----------------
__device__ __forceinline__ float wave_reduce_sum(float v) {
#pragma unroll
  for (int off = 32; off; off >>= 1) v += __shfl_down(v, off, 64);
  return v;
}
__device__ __forceinline__ float wave_reduce_max(float v) {
#pragma unroll
  for (int off = 32; off; off >>= 1) v = fmaxf(v, __shfl_down(v, off, 64));
  return v;
}
__device__ __forceinline__ float tanh_fast(float x) {
  // 1 - 2/(e^{2x}+1); inf/0 limits give +-1 correctly
  const float e = __expf(2.f * x);
  return 1.f - __fdividef(2.f, e + 1.f);
}
__device__ __forceinline__ float sigmoid_fast(float x) {
  return __fdividef(1.f, 1.f + __expf(-x));
}

// ---------------- gather: x = [embed_item[cand], embed_user[user]] ----------------
__global__ void gather_x(const int* __restrict__ users, const int* __restrict__ cand,
                         const float* __restrict__ eu, const float* __restrict__ ei,
                         float* __restrict__ x)
{
  int idx = blockIdx.x * 256 + threadIdx.x;          // B*S*H = 8388608
  int h  = idx & (H_ - 1);
  int bs = idx >> 8;                                  // b*S + s
  int b  = bs >> 9;
  float v;
  if (h < DI_) v = ei[(long)cand[bs] * DI_ + h];
  else         v = eu[(long)users[b] * DU_ + (h - DI_)];
  x[idx] = v;
}

// ---------------- tiled fp32 GEMM 128x128x16, 8x8/thread ----------------
#define BM 128
#define BN 128
#define BK 16

template<bool NT, bool RELU>
__global__ __launch_bounds__(256) void gemm_kernel(
    const float* __restrict__ A, const float* __restrict__ Bm,
    const float* __restrict__ bias, float* __restrict__ C,
    int M, int N, int Kd, int ldA, int ldB, int ldC,
    long sA, long sB, long sC)
{
  __shared__ float As[BK][BM + 4];
  __shared__ float Bs[BK][BN + 4];
  const int bx = blockIdx.x, by = blockIdx.y, bz = blockIdx.z;
  A  += (long)bz * sA;
  Bm += (long)bz * sB;
  C  += (long)bz * sC;
  const int tid = threadIdx.x;
  const int tx = tid & 15, ty = tid >> 4;
  float acc[8][8] = {};

  const int arow  = tid >> 1;            // 0..127
  const int acol8 = (tid & 1) * 8;       // 0 or 8

  for (int k0 = 0; k0 < Kd; k0 += BK) {
    // A tile: 128 x 16 (K contiguous in source)
    {
      const float* ap = A + (long)(by * BM + arow) * ldA + k0 + acol8;
      const float4 av0 = *(const float4*)(ap);
      const float4 av1 = *(const float4*)(ap + 4);
      As[acol8 + 0][arow] = av0.x; As[acol8 + 1][arow] = av0.y;
      As[acol8 + 2][arow] = av0.z; As[acol8 + 3][arow] = av0.w;
      As[acol8 + 4][arow] = av1.x; As[acol8 + 5][arow] = av1.y;
      As[acol8 + 6][arow] = av1.z; As[acol8 + 7][arow] = av1.w;
    }
    if (!NT) {
      const int brow = tid >> 4, bcol8 = (tid & 15) * 8;
      const float* bp = Bm + (long)(k0 + brow) * ldB + bx * BN + bcol8;
      *(float4*)&Bs[brow][bcol8]     = *(const float4*)(bp);
      *(float4*)&Bs[brow][bcol8 + 4] = *(const float4*)(bp + 4);
    } else {
      const int bn = tid >> 1, bk8 = (tid & 1) * 8;
      const float* bp = Bm + (long)(bx * BN + bn) * ldB + k0 + bk8;
      const float4 bv0 = *(const float4*)(bp);
      const float4 bv1 = *(const float4*)(bp + 4);
      Bs[bk8 + 0][bn] = bv0.x; Bs[bk8 + 1][bn] = bv0.y;
      Bs[bk8 + 2][bn] = bv0.z; Bs[bk8 + 3][bn] = bv0.w;
      Bs[bk8 + 4][bn] = bv1.x; Bs[bk8 + 5][bn] = bv1.y;
      Bs[bk8 + 6][bn] = bv1.z; Bs[bk8 + 7][bn] = bv1.w;
    }
    __syncthreads();
#pragma unroll
    for (int kk = 0; kk < BK; ++kk) {
      const float4 A0 = *(const float4*)&As[kk][ty * 4];
      const float4 A1 = *(const float4*)&As[kk][ty * 4 + 64];
      const float4 B0 = *(const float4*)&Bs[kk][tx * 4];
      const float4 B1 = *(const float4*)&Bs[kk][tx * 4 + 64];
      const float a[8] = {A0.x, A0.y, A0.z, A0.w, A1.x, A1.y, A1.z, A1.w};
      const float b[8] = {B0.x, B0.y, B0.z, B0.w, B1.x, B1.y, B1.z, B1.w};
#pragma unroll
      for (int i = 0; i < 8; ++i)
#pragma unroll
        for (int j = 0; j < 8; ++j)
          acc[i][j] += a[i] * b[j];
    }
    __syncthreads();
  }

  const int col0 = bx * BN + tx * 4;
  float4 bias0 = make_float4(0.f, 0.f, 0.f, 0.f), bias1 = bias0;
  if (bias) {
    bias0 = *(const float4*)(bias + col0);
    bias1 = *(const float4*)(bias + col0 + 64);
  }
#pragma unroll
  for (int i = 0; i < 8; ++i) {
    const int row = by * BM + (i >> 2) * 64 + ty * 4 + (i & 3);
    float4 o0, o1;
    o0.x = acc[i][0] + bias0.x; o0.y = acc[i][1] + bias0.y;
    o0.z = acc[i][2] + bias0.z; o0.w = acc[i][3] + bias0.w;
    o1.x = acc[i][4] + bias1.x; o1.y = acc[i][5] + bias1.y;
    o1.z = acc[i][6] + bias1.z; o1.w = acc[i][7] + bias1.w;
    if (RELU) {
      o0.x = fmaxf(o0.x, 0.f); o0.y = fmaxf(o0.y, 0.f);
      o0.z = fmaxf(o0.z, 0.f); o0.w = fmaxf(o0.w, 0.f);
      o1.x = fmaxf(o1.x, 0.f); o1.y = fmaxf(o1.y, 0.f);
      o1.z = fmaxf(o1.z, 0.f); o1.w = fmaxf(o1.w, 0.f);
    }
    *(float4*)(C + (long)row * ldC + col0)      = o0;
    *(float4*)(C + (long)row * ldC + col0 + 64) = o1;
  }
}

// ---------------- attention softmax (rows of length 512, scaled by 1/16) ----------------
__global__ __launch_bounds__(256) void attn_softmax(float* __restrict__ att)
{
  __shared__ float red[8];
  const long row = blockIdx.x;
  float* p = att + row * S_;
  const int t = threadIdx.x, lane = t & 63, wid = t >> 6;
  float v0 = p[t] * 0.0625f, v1 = p[t + 256] * 0.0625f;
  float m = wave_reduce_max(fmaxf(v0, v1));
  if (!lane) red[wid] = m;
  __syncthreads();
  const float bm = fmaxf(fmaxf(red[0], red[1]), fmaxf(red[2], red[3]));
  const float e0 = __expf(v0 - bm), e1 = __expf(v1 - bm);
  float s = wave_reduce_sum(e0 + e1);
  __syncthreads();
  if (!lane) red[wid] = s;
  __syncthreads();
  const float inv = __fdividef(1.f, red[0] + red[1] + red[2] + red[3]);
  p[t] = e0 * inv; p[t + 256] = e1 * inv;
}

// ---------------- residual + layernorm (in-place into x) ----------------
__global__ __launch_bounds__(256) void ln_res(float* __restrict__ x, const float* __restrict__ y,
                                              const float* __restrict__ g, const float* __restrict__ b)
{
  __shared__ float red[8];
  const long row = blockIdx.x;
  const int t = threadIdx.x, lane = t & 63, wid = t >> 6;
  float v = x[row * H_ + t] + y[row * H_ + t];
  float s = wave_reduce_sum(v);
  if (!lane) red[wid] = s;
  __syncthreads();
  const float mean = (red[0] + red[1] + red[2] + red[3]) * (1.f / H_);
  const float d = v - mean;
  float s2 = wave_reduce_sum(d * d);
  __syncthreads();
  if (!lane) red[wid] = s2;
  __syncthreads();
  const float var = (red[0] + red[1] + red[2] + red[3]) * (1.f / H_);
  x[row * H_ + t] = d * rsqrtf(var + 1e-5f) * g[t] + b[t];
}

// ---------------- batched transpose (b,s,h) -> (b,h,s) ----------------
__global__ __launch_bounds__(256) void transpose_bsh(const float* __restrict__ in, float* __restrict__ out)
{
  __shared__ float tile[32][33];
  const int b = blockIdx.z, s0 = blockIdx.x * 32, h0 = blockIdx.y * 32;
  const int tx = threadIdx.x & 31, ty = threadIdx.x >> 5;    // ty 0..7
  const float* ip = in + ((long)b * S_ + s0) * H_ + h0;
#pragma unroll
  for (int i = 0; i < 4; ++i)
    tile[ty + 8 * i][tx] = ip[(long)(ty + 8 * i) * H_ + tx];
  __syncthreads();
  float* op = out + ((long)b * H_ + h0) * S_ + s0;
#pragma unroll
  for (int i = 0; i < 4; ++i)
    op[(long)(ty + 8 * i) * S_ + tx] = tile[tx][ty + 8 * i];
}

// ---------------- gather LSTM inputs (K,B,H), step 0 zeroed ----------------
__global__ void gather_inputs(const int* __restrict__ tidx, const float* __restrict__ enc,
                              float* __restrict__ inp)
{
  int idx = blockIdx.x * 256 + threadIdx.x;          // K*B*H = 262144
  int h = idx & 255, kb = idx >> 8;
  int b = kb & 63, k = kb >> 6;
  float v = 0.f;
  if (k > 0) {
    int s = tidx[b * K_ + k];
    v = enc[((long)b * S_ + s) * H_ + h];
  }
  inp[idx] = v;
}

// ---------------- transpose W_hh (4H x H) -> (H x 4H) ----------------
__global__ void transpose_whh(const float* __restrict__ W, float* __restrict__ WT)
{
  int idx = blockIdx.x * 256 + threadIdx.x;          // 262144
  int r = idx >> 8, d = idx & 255;
  WT[d * H4_ + r] = W[idx];
}

// ---------------- fused LSTM: one block per batch row, all 16 steps ----------------
__global__ __launch_bounds__(1024) void lstm_all(const float* __restrict__ Xp,
                                                 const float* __restrict__ WhhT,
                                                 const float* __restrict__ b_hh,
                                                 float* __restrict__ dec)
{
  __shared__ float hs[H_];
  __shared__ float gates[H4_];
  const int b = blockIdx.x, j = threadIdx.x;          // j in [0,1024)
  float c = 0.f;
  if (j < H_) hs[j] = 0.f;
  const float bh = b_hh[j];
  __syncthreads();
  for (int step = 0; step < K_; ++step) {
    float acc = Xp[((long)step * B_ + b) * H4_ + j] + bh;
#pragma unroll 8
    for (int d = 0; d < H_; ++d)
      acc += hs[d] * WhhT[d * H4_ + j];
    gates[j] = acc;
    __syncthreads();
    if (j < H_) {
      const float gi = gates[j], gf = gates[256 + j], gg = gates[512 + j], go = gates[768 + j];
      c = sigmoid_fast(gf) * c + sigmoid_fast(gi) * tanh_fast(gg);
      const float h = sigmoid_fast(go) * tanh_fast(c);
      hs[j] = h;
      const long rw = ((long)step * B_ + b) * (2 * H_);
      dec[rw + j] = h;
      dec[rw + H_ + j] = c;
    }
    __syncthreads();
  }
}

// ---------------- glimpse: per-lane-s scores, softmax, weighted sum ----------------
__global__ __launch_bounds__(256) void glimpse_kernel(
    const float* __restrict__ decW1, const float* __restrict__ encW2T,
    const float* __restrict__ enc, const float* __restrict__ bias1,
    const float* __restrict__ V1, float* __restrict__ glim)
{
  __shared__ float dv[H_], vd[H_], sc[S_], red[8];
  const int bid = blockIdx.x;                // k*B + b
  const int b = bid & 63;
  const int t = threadIdx.x, lane = t & 63, wv = t >> 6;
  dv[t] = decW1[(long)bid * H_ + t] + bias1[t];
  vd[t] = V1[t];
  __syncthreads();
  const float* ebase = encW2T + (long)b * H_ * S_;
  float a0 = 0.f, a1 = 0.f;
#pragma unroll 4
  for (int h = 0; h < H_; ++h) {
    const float d = dv[h], w = vd[h];
    const float* r = ebase + (long)h * S_;
    a0 += tanh_fast(d + r[t]) * w;
    a1 += tanh_fast(d + r[t + 256]) * w;
  }
  // softmax over the 512 scores of this block
  float m = wave_reduce_max(fmaxf(a0, a1));
  if (!lane) red[wv] = m;
  __syncthreads();
  const float bm = fmaxf(fmaxf(red[0], red[1]), fmaxf(red[2], red[3]));
  const float e0 = __expf(a0 - bm), e1 = __expf(a1 - bm);
  float ssum = wave_reduce_sum(e0 + e1);
  __syncthreads();
  if (!lane) red[wv] = ssum;
  __syncthreads();
  const float inv = __fdividef(1.f, red[0] + red[1] + red[2] + red[3]);
  sc[t] = e0 * inv; sc[t + 256] = e1 * inv;
  __syncthreads();
  // weighted sum: glim[bid][t] = sum_s sc[s] * enc[b][s][t]
  float acc = 0.f;
  const float* eb = enc + (long)b * S_ * H_ + t;
#pragma unroll 4
  for (int s = 0; s < S_; ++s) acc += sc[s] * eb[(long)s * H_];
  glim[(long)bid * H_ + t] = acc;
}

// ---------------- gcat = [dec | glim] ----------------
__global__ void concat_gcat(const float* __restrict__ dec, const float* __restrict__ glim,
                            float* __restrict__ gcat)
{
  int idx = blockIdx.x * 256 + threadIdx.x;   // 1024*768
  int j = idx % 768, row = idx / 768;
  gcat[idx] = (j < 512) ? dec[(long)row * 512 + j] : glim[(long)row * 256 + (j - 512)];
}

// ---------------- pointer logits -> out[b,k,s] ----------------
__global__ __launch_bounds__(256) void pointer_kernel(
    const float* __restrict__ gW3, const float* __restrict__ encW4T,
    const float* __restrict__ bias2, const float* __restrict__ V2,
    float* __restrict__ out)
{
  __shared__ float dv[H_], vd[H_];
  const int bid = blockIdx.x;                // k*B + b
  const int b = bid & 63, k = bid >> 6;
  const int t = threadIdx.x;
  dv[t] = gW3[(long)bid * H_ + t] + bias2[t];
  vd[t] = V2[t];
  __syncthreads();
  const float* ebase = encW4T + (long)b * H_ * S_;
  float a0 = 0.f, a1 = 0.f;
#pragma unroll 4
  for (int h = 0; h < H_; ++h) {
    const float d = dv[h], w = vd[h];
    const float* r = ebase + (long)h * S_;
    a0 += tanh_fast(d + r[t]) * w;
    a1 += tanh_fast(d + r[t + 256]) * w;
  }
  const long ro = ((long)b * K_ + k) * S_;
  out[ro + t] = a0;
  out[ro + 256 + t] = a1;
}

// ---------------- host ----------------
extern "C" void kernel_launch(void* const* d_in, const int* in_sizes, int n_in,
                              void* d_out, int out_size, void* d_ws, size_t ws_size,
                              hipStream_t stream)
{
  const int*   users = (const int*)d_in[0];
  const int*   cand  = (const int*)d_in[1];
  const int*   tidx  = (const int*)d_in[2];
  const float* eu    = (const float*)d_in[3];
  const float* ei    = (const float*)d_in[4];
  const float* Wq    = (const float*)d_in[5];
  const float* bq    = (const float*)d_in[6];
  const float* Wk    = (const float*)d_in[7];
  const float* bk    = (const float*)d_in[8];
  const float* Wv    = (const float*)d_in[9];
  const float* bv    = (const float*)d_in[10];
  const float* Wo    = (const float*)d_in[11];
  const float* bo    = (const float*)d_in[12];
  const float* ln1g  = (const float*)d_in[13];
  const float* ln1b  = (const float*)d_in[14];
  const float* Wf1   = (const float*)d_in[15];
  const float* bf1   = (const float*)d_in[16];
  const float* Wf2   = (const float*)d_in[17];
  const float* bf2   = (const float*)d_in[18];
  const float* ln2g  = (const float*)d_in[19];
  const float* ln2b  = (const float*)d_in[20];
  const float* W_ih  = (const float*)d_in[21];
  const float* W_hh  = (const float*)d_in[22];
  const float* b_ih  = (const float*)d_in[23];
  const float* b_hh  = (const float*)d_in[24];
  const float* W_D1  = (const float*)d_in[25];
  const float* W_D2  = (const float*)d_in[26];
  const float* bias1 = (const float*)d_in[27];
  const float* V_D1  = (const float*)d_in[28];
  const float* W_D3  = (const float*)d_in[29];
  const float* W_D4  = (const float*)d_in[30];
  const float* bias2 = (const float*)d_in[31];
  const float* V_D2  = (const float*)d_in[32];

  float* ws = (float*)d_ws;
  const long XSZ  = (long)B_ * S_ * H_;        // 8388608 floats
  float* x    = ws;                            // enc lives here at the end
  float* qb   = x  + XSZ;                      // q / Wo-out / encW2 / encW4T
  float* kb   = qb + XSZ;                      // k / FFN mid / encW4
  float* vb   = kb + XSZ;                      // v / small arena
  float* ao   = vb + XSZ;                      // attn out / encW2T
  float* attc = ao + XSZ;                      // att chunk / FFN y2 chunk
  // small arena (inside vb, used after attention phase)
  float* inp    = vb;                          // 262144
  float* Xp     = inp  + 262144;               // 1048576
  float* WhhT   = Xp   + 1048576;              // 262144
  float* dec    = WhhT + 262144;               // 524288
  float* decW1  = dec  + 524288;               // 262144
  float* glim   = decW1 + 262144;              // 262144
  float* gcat   = glim + 262144;               // 786432
  float* gcatW3 = gcat + 786432;               // 262144

  float* out = (float*)d_out;

  // 1. gather x
  gather_x<<<dim3(32768), dim3(256), 0, stream>>>(users, cand, eu, ei, x);

  // 2. q,k,v projections
  gemm_kernel<false,false><<<dim3(2,256), dim3(256), 0, stream>>>(x, Wq, bq, qb, 32768, H_, H_, H_, H_, H_, 0,0,0);
  gemm_kernel<false,false><<<dim3(2,256), dim3(256), 0, stream>>>(x, Wk, bk, kb, 32768, H_, H_, H_, H_, H_, 0,0,0);
  gemm_kernel<false,false><<<dim3(2,256), dim3(256), 0, stream>>>(x, Wv, bv, vb, 32768, H_, H_, H_, H_, H_, 0,0,0);

  // 3. attention, 4 chunks of 16 batches
  for (int c = 0; c < 4; ++c) {
    const long qoff = (long)c * 16 * S_ * H_;
    gemm_kernel<true,false><<<dim3(4,4,16), dim3(256), 0, stream>>>(
        qb + qoff, kb + qoff, nullptr, attc, S_, S_, H_, H_, H_, S_,
        (long)S_*H_, (long)S_*H_, (long)S_*S_);
    attn_softmax<<<dim3(16*S_), dim3(256), 0, stream>>>(attc);
    gemm_kernel<false,false><<<dim3(2,4,16), dim3(256), 0, stream>>>(
        attc, vb + qoff, nullptr, ao + qoff, S_, H_, S_, S_, H_, H_,
        (long)S_*S_, (long)S_*H_, (long)S_*H_);
  }

  // 4. Wo projection + residual LN1 (y into qb region)
  gemm_kernel<false,false><<<dim3(2,256), dim3(256), 0, stream>>>(ao, Wo, bo, qb, 32768, H_, H_, H_, H_, H_, 0,0,0);
  ln_res<<<dim3(32768), dim3(256), 0, stream>>>(x, qb, ln1g, ln1b);

  // 5. FFN, 4 chunks of 8192 rows (mid in kb, y2 in attc)
  for (int c = 0; c < 4; ++c) {
    float* xc = x + (long)c * 8192 * H_;
    gemm_kernel<false,true ><<<dim3(8,64), dim3(256), 0, stream>>>(xc, Wf1, bf1, kb, 8192, H4_, H_, H_, H4_, H4_, 0,0,0);
    gemm_kernel<false,false><<<dim3(2,64), dim3(256), 0, stream>>>(kb, Wf2, bf2, attc, 8192, H_, H4_, H4_, H_, H_, 0,0,0);
    ln_res<<<dim3(8192), dim3(256), 0, stream>>>(xc, attc, ln2g, ln2b);
  }
  // x now holds enc

  // 6. enc @ W_D2 -> qb, enc @ W_D4 -> kb; transpose to (b,h,s)
  gemm_kernel<false,false><<<dim3(2,256), dim3(256), 0, stream>>>(x, W_D2, nullptr, qb, 32768, H_, H_, H_, H_, H_, 0,0,0);
  gemm_kernel<false,false><<<dim3(2,256), dim3(256), 0, stream>>>(x, W_D4, nullptr, kb, 32768, H_, H_, H_, H_, H_, 0,0,0);
  transpose_bsh<<<dim3(16,8,64), dim3(256), 0, stream>>>(qb, ao);   // encW2T -> ao
  transpose_bsh<<<dim3(16,8,64), dim3(256), 0, stream>>>(kb, qb);   // encW4T -> qb

  // 7. LSTM
  gather_inputs<<<dim3(1024), dim3(256), 0, stream>>>(tidx, x, inp);
  gemm_kernel<true,false><<<dim3(8,8), dim3(256), 0, stream>>>(inp, W_ih, b_ih, Xp, K_*B_, H4_, H_, H_, H_, H4_, 0,0,0);
  transpose_whh<<<dim3(1024), dim3(256), 0, stream>>>(W_hh, WhhT);
  lstm_all<<<dim3(B_), dim3(1024), 0, stream>>>(Xp, WhhT, b_hh, dec);

  // 8. glimpse
  gemm_kernel<false,false><<<dim3(2,8), dim3(256), 0, stream>>>(dec, W_D1, nullptr, decW1, K_*B_, H_, 2*H_, 2*H_, H_, H_, 0,0,0);
  glimpse_kernel<<<dim3(K_*B_), dim3(256), 0, stream>>>(decW1, ao, x, bias1, V_D1, glim);

  // 9. pointer
  concat_gcat<<<dim3(3072), dim3(256), 0, stream>>>(dec, glim, gcat);
  gemm_kernel<false,false><<<dim3(2,8), dim3(256), 0, stream>>>(gcat, W_D3, nullptr, gcatW3, K_*B_, H_, 3*H_, 3*H_, H_, H_, 0,0,0);
  pointer_kernel<<<dim3(K_*B_), dim3(256), 0, stream>>>(gcatW3, qb, bias2, V_D2, out);
}

// Round 4
// 2398.676 us; speedup vs baseline: 1.0049x; 1.0006x over previous
//
#include <hip/hip_runtime.h>
#include <hip/hip_bf16.h>
#include <math.h>

#define B_   64
#define S_   512
#define K_   16
#define DU_  64
#define DI_  192
#define H_   256
#define H4_  1024

// ---------------- helpers ----------------
__device__ __forceinline__ float wave_reduce_sum(float v) {
#pragma unroll
  for (int off = 32; off; off >>= 1) v += __shfl_down(v, off, 64);
  return v;
}
__device__ __forceinline__ float wave_reduce_max(float v) {
#pragma unroll
  for (int off = 32; off; off >>= 1) v = fmaxf(v, __shfl_down(v, off, 64));
  return v;
}
__device__ __forceinline__ float tanh_fast(float x) {
  const float e = __expf(2.f * x);
  return 1.f - __fdividef(2.f, e + 1.f);
}
__device__ __forceinline__ float sigmoid_fast(float x) {
  return __fdividef(1.f, 1.f + __expf(-x));
}

// ---------------- gather: x = [embed_item[cand], embed_user[user]] ----------------
__global__ void gather_x(const int* __restrict__ users, const int* __restrict__ cand,
                         const float* __restrict__ eu, const float* __restrict__ ei,
                         float* __restrict__ x)
{
  int idx = blockIdx.x * 256 + threadIdx.x;          // B*S*H = 8388608
  int h  = idx & (H_ - 1);
  int bs = idx >> 8;                                  // b*S + s
  int b  = bs >> 9;
  float v;
  if (h < DI_) v = ei[(long)cand[bs] * DI_ + h];
  else         v = eu[(long)users[b] * DU_ + (h - DI_)];
  x[idx] = v;
}

// ---------------- tiled fp32 GEMM 128x128x16, 8x8/thread, named-scalar acc ----------------
#define BM 128
#define BN 128
#define BK 16

// FMA of scalar s against float4 b into named float4 c
#define FMA4(c, s, b) { c.x += (s)*(b).x; c.y += (s)*(b).y; c.z += (s)*(b).z; c.w += (s)*(b).w; }
#define ROW2(cL, cH, s) FMA4(cL, s, b0) FMA4(cH, s, b1)

template<bool NT, bool RELU>
__global__ __launch_bounds__(256, 4) void gemm_kernel(
    const float* __restrict__ A, const float* __restrict__ Bm,
    const float* __restrict__ bias, float* __restrict__ C,
    int M, int N, int Kd, int ldA, int ldB, int ldC,
    long sA, long sB, long sC)
{
  __shared__ float As[BK][BM + 4];
  __shared__ float Bs[BK][BN + 4];
  const int bx = blockIdx.x, by = blockIdx.y, bz = blockIdx.z;
  A  += (long)bz * sA;
  Bm += (long)bz * sB;
  C  += (long)bz * sC;
  const int tid = threadIdx.x;
  const int tx = tid & 15, ty = tid >> 4;

  // 16 named float4 accumulators: rows ty*4+{0..3} (L0..3 cols tx*4.., H0..3 cols tx*4+64),
  // rows 64+ty*4+{0..3} (L4..7 / H4..7)
  float4 cL0 = {0,0,0,0}, cL1 = {0,0,0,0}, cL2 = {0,0,0,0}, cL3 = {0,0,0,0};
  float4 cL4 = {0,0,0,0}, cL5 = {0,0,0,0}, cL6 = {0,0,0,0}, cL7 = {0,0,0,0};
  float4 cH0 = {0,0,0,0}, cH1 = {0,0,0,0}, cH2 = {0,0,0,0}, cH3 = {0,0,0,0};
  float4 cH4 = {0,0,0,0}, cH5 = {0,0,0,0}, cH6 = {0,0,0,0}, cH7 = {0,0,0,0};

  const int arow  = tid >> 1;            // 0..127
  const int acol8 = (tid & 1) * 8;       // 0 or 8

  for (int k0 = 0; k0 < Kd; k0 += BK) {
    // A tile: 128 x 16 (K contiguous in source)
    {
      const float* ap = A + (long)(by * BM + arow) * ldA + k0 + acol8;
      const float4 av0 = *(const float4*)(ap);
      const float4 av1 = *(const float4*)(ap + 4);
      As[acol8 + 0][arow] = av0.x; As[acol8 + 1][arow] = av0.y;
      As[acol8 + 2][arow] = av0.z; As[acol8 + 3][arow] = av0.w;
      As[acol8 + 4][arow] = av1.x; As[acol8 + 5][arow] = av1.y;
      As[acol8 + 6][arow] = av1.z; As[acol8 + 7][arow] = av1.w;
    }
    if (!NT) {
      const int brow = tid >> 4, bcol8 = (tid & 15) * 8;
      const float* bp = Bm + (long)(k0 + brow) * ldB + bx * BN + bcol8;
      *(float4*)&Bs[brow][bcol8]     = *(const float4*)(bp);
      *(float4*)&Bs[brow][bcol8 + 4] = *(const float4*)(bp + 4);
    } else {
      const int bn = tid >> 1, bk8 = (tid & 1) * 8;
      const float* bp = Bm + (long)(bx * BN + bn) * ldB + k0 + bk8;
      const float4 bv0 = *(const float4*)(bp);
      const float4 bv1 = *(const float4*)(bp + 4);
      Bs[bk8 + 0][bn] = bv0.x; Bs[bk8 + 1][bn] = bv0.y;
      Bs[bk8 + 2][bn] = bv0.z; Bs[bk8 + 3][bn] = bv0.w;
      Bs[bk8 + 4][bn] = bv1.x; Bs[bk8 + 5][bn] = bv1.y;
      Bs[bk8 + 6][bn] = bv1.z; Bs[bk8 + 7][bn] = bv1.w;
    }
    __syncthreads();
#pragma unroll
    for (int kk = 0; kk < BK; ++kk) {
      const float4 a0 = *(const float4*)&As[kk][ty * 4];
      const float4 a1 = *(const float4*)&As[kk][ty * 4 + 64];
      const float4 b0 = *(const float4*)&Bs[kk][tx * 4];
      const float4 b1 = *(const float4*)&Bs[kk][tx * 4 + 64];
      ROW2(cL0, cH0, a0.x) ROW2(cL1, cH1, a0.y) ROW2(cL2, cH2, a0.z) ROW2(cL3, cH3, a0.w)
      ROW2(cL4, cH4, a1.x) ROW2(cL5, cH5, a1.y) ROW2(cL6, cH6, a1.z) ROW2(cL7, cH7, a1.w)
    }
    __syncthreads();
  }

  const int col0 = bx * BN + tx * 4;
  float4 bias0 = make_float4(0.f, 0.f, 0.f, 0.f), bias1 = bias0;
  if (bias) {
    bias0 = *(const float4*)(bias + col0);
    bias1 = *(const float4*)(bias + col0 + 64);
  }
#define EPILOG(cL, cH, rowexpr)                                              \
  { const int row = by * BM + (rowexpr);                                     \
    float4 o0, o1;                                                           \
    o0.x = cL.x + bias0.x; o0.y = cL.y + bias0.y;                            \
    o0.z = cL.z + bias0.z; o0.w = cL.w + bias0.w;                            \
    o1.x = cH.x + bias1.x; o1.y = cH.y + bias1.y;                            \
    o1.z = cH.z + bias1.z; o1.w = cH.w + bias1.w;                            \
    if (RELU) {                                                              \
      o0.x = fmaxf(o0.x, 0.f); o0.y = fmaxf(o0.y, 0.f);                      \
      o0.z = fmaxf(o0.z, 0.f); o0.w = fmaxf(o0.w, 0.f);                      \
      o1.x = fmaxf(o1.x, 0.f); o1.y = fmaxf(o1.y, 0.f);                      \
      o1.z = fmaxf(o1.z, 0.f); o1.w = fmaxf(o1.w, 0.f);                      \
    }                                                                        \
    *(float4*)(C + (long)row * ldC + col0)      = o0;                        \
    *(float4*)(C + (long)row * ldC + col0 + 64) = o1;                        \
  }
  EPILOG(cL0, cH0, ty * 4 + 0)      EPILOG(cL1, cH1, ty * 4 + 1)
  EPILOG(cL2, cH2, ty * 4 + 2)      EPILOG(cL3, cH3, ty * 4 + 3)
  EPILOG(cL4, cH4, 64 + ty * 4 + 0) EPILOG(cL5, cH5, 64 + ty * 4 + 1)
  EPILOG(cL6, cH6, 64 + ty * 4 + 2) EPILOG(cL7, cH7, 64 + ty * 4 + 3)
#undef EPILOG
}

// ---------------- attention softmax (rows of length 512, scaled by 1/16) ----------------
__global__ __launch_bounds__(256) void attn_softmax(float* __restrict__ att)
{
  __shared__ float red[8];
  const long row = blockIdx.x;
  float* p = att + row * S_;
  const int t = threadIdx.x, lane = t & 63, wid = t >> 6;
  float v0 = p[t] * 0.0625f, v1 = p[t + 256] * 0.0625f;
  float m = wave_reduce_max(fmaxf(v0, v1));
  if (!lane) red[wid] = m;
  __syncthreads();
  const float bm = fmaxf(fmaxf(red[0], red[1]), fmaxf(red[2], red[3]));
  const float e0 = __expf(v0 - bm), e1 = __expf(v1 - bm);
  float s = wave_reduce_sum(e0 + e1);
  __syncthreads();
  if (!lane) red[wid] = s;
  __syncthreads();
  const float inv = __fdividef(1.f, red[0] + red[1] + red[2] + red[3]);
  p[t] = e0 * inv; p[t + 256] = e1 * inv;
}

// ---------------- residual + layernorm (in-place into x) ----------------
__global__ __launch_bounds__(256) void ln_res(float* __restrict__ x, const float* __restrict__ y,
                                              const float* __restrict__ g, const float* __restrict__ b)
{
  __shared__ float red[8];
  const long row = blockIdx.x;
  const int t = threadIdx.x, lane = t & 63, wid = t >> 6;
  float v = x[row * H_ + t] + y[row * H_ + t];
  float s = wave_reduce_sum(v);
  if (!lane) red[wid] = s;
  __syncthreads();
  const float mean = (red[0] + red[1] + red[2] + red[3]) * (1.f / H_);
  const float d = v - mean;
  float s2 = wave_reduce_sum(d * d);
  __syncthreads();
  if (!lane) red[wid] = s2;
  __syncthreads();
  const float var = (red[0] + red[1] + red[2] + red[3]) * (1.f / H_);
  x[row * H_ + t] = d * rsqrtf(var + 1e-5f) * g[t] + b[t];
}

// ---------------- batched transpose (b,s,h) -> (b,h,s) ----------------
__global__ __launch_bounds__(256) void transpose_bsh(const float* __restrict__ in, float* __restrict__ out)
{
  __shared__ float tile[32][33];
  const int b = blockIdx.z, s0 = blockIdx.x * 32, h0 = blockIdx.y * 32;
  const int tx = threadIdx.x & 31, ty = threadIdx.x >> 5;    // ty 0..7
  const float* ip = in + ((long)b * S_ + s0) * H_ + h0;
#pragma unroll
  for (int i = 0; i < 4; ++i)
    tile[ty + 8 * i][tx] = ip[(long)(ty + 8 * i) * H_ + tx];
  __syncthreads();
  float* op = out + ((long)b * H_ + h0) * S_ + s0;
#pragma unroll
  for (int i = 0; i < 4; ++i)
    op[(long)(ty + 8 * i) * S_ + tx] = tile[tx][ty + 8 * i];
}

// ---------------- gather LSTM inputs (K,B,H), step 0 zeroed ----------------
__global__ void gather_inputs(const int* __restrict__ tidx, const float* __restrict__ enc,
                              float* __restrict__ inp)
{
  int idx = blockIdx.x * 256 + threadIdx.x;          // K*B*H = 262144
  int h = idx & 255, kb = idx >> 8;
  int b = kb & 63, k = kb >> 6;
  float v = 0.f;
  if (k > 0) {
    int s = tidx[b * K_ + k];
    v = enc[((long)b * S_ + s) * H_ + h];
  }
  inp[idx] = v;
}

// ---------------- transpose W_hh (4H x H) -> (H x 4H) ----------------
__global__ void transpose_whh(const float* __restrict__ W, float* __restrict__ WT)
{
  int idx = blockIdx.x * 256 + threadIdx.x;          // 262144
  int r = idx >> 8, d = idx & 255;
  WT[d * H4_ + r] = W[idx];
}

// ---------------- fused LSTM: one block per batch row, all 16 steps ----------------
__global__ __launch_bounds__(1024) void lstm_all(const float* __restrict__ Xp,
                                                 const float* __restrict__ WhhT,
                                                 const float* __restrict__ b_hh,
                                                 float* __restrict__ dec)
{
  __shared__ float hs[H_];
  __shared__ float gates[H4_];
  const int b = blockIdx.x, j = threadIdx.x;          // j in [0,1024)
  float c = 0.f;
  if (j < H_) hs[j] = 0.f;
  const float bh = b_hh[j];
  __syncthreads();
  for (int step = 0; step < K_; ++step) {
    float acc = Xp[((long)step * B_ + b) * H4_ + j] + bh;
#pragma unroll 8
    for (int d = 0; d < H_; ++d)
      acc += hs[d] * WhhT[d * H4_ + j];
    gates[j] = acc;
    __syncthreads();
    if (j < H_) {
      const float gi = gates[j], gf = gates[256 + j], gg = gates[512 + j], go = gates[768 + j];
      c = sigmoid_fast(gf) * c + sigmoid_fast(gi) * tanh_fast(gg);
      const float h = sigmoid_fast(go) * tanh_fast(c);
      hs[j] = h;
      const long rw = ((long)step * B_ + b) * (2 * H_);
      dec[rw + j] = h;
      dec[rw + H_ + j] = c;
    }
    __syncthreads();
  }
}

// ---------------- glimpse: per-lane-s scores, softmax, weighted sum ----------------
__global__ __launch_bounds__(256) void glimpse_kernel(
    const float* __restrict__ decW1, const float* __restrict__ encW2T,
    const float* __restrict__ enc, const float* __restrict__ bias1,
    const float* __restrict__ V1, float* __restrict__ glim)
{
  __shared__ float dv[H_], vd[H_], sc[S_], red[8];
  const int bid = blockIdx.x;                // k*B + b
  const int b = bid & 63;
  const int t = threadIdx.x, lane = t & 63, wv = t >> 6;
  dv[t] = decW1[(long)bid * H_ + t] + bias1[t];
  vd[t] = V1[t];
  __syncthreads();
  const float* ebase = encW2T + (long)b * H_ * S_;
  float a0 = 0.f, a1 = 0.f;
#pragma unroll 4
  for (int h = 0; h < H_; ++h) {
    const float d = dv[h], w = vd[h];
    const float* r = ebase + (long)h * S_;
    a0 += tanh_fast(d + r[t]) * w;
    a1 += tanh_fast(d + r[t + 256]) * w;
  }
  // softmax over the 512 scores of this block
  float m = wave_reduce_max(fmaxf(a0, a1));
  if (!lane) red[wv] = m;
  __syncthreads();
  const float bm = fmaxf(fmaxf(red[0], red[1]), fmaxf(red[2], red[3]));
  const float e0 = __expf(a0 - bm), e1 = __expf(a1 - bm);
  float ssum = wave_reduce_sum(e0 + e1);
  __syncthreads();
  if (!lane) red[wv] = ssum;
  __syncthreads();
  const float inv = __fdividef(1.f, red[0] + red[1] + red[2] + red[3]);
  sc[t] = e0 * inv; sc[t + 256] = e1 * inv;
  __syncthreads();
  // weighted sum: glim[bid][t] = sum_s sc[s] * enc[b][s][t]
  float acc = 0.f;
  const float* eb = enc + (long)b * S_ * H_ + t;
#pragma unroll 4
  for (int s = 0; s < S_; ++s) acc += sc[s] * eb[(long)s * H_];
  glim[(long)bid * H_ + t] = acc;
}

// ---------------- gcat = [dec | glim] ----------------
__global__ void concat_gcat(const float* __restrict__ dec, const float* __restrict__ glim,
                            float* __restrict__ gcat)
{
  int idx = blockIdx.x * 256 + threadIdx.x;   // 1024*768
  int j = idx % 768, row = idx / 768;
  gcat[idx] = (j < 512) ? dec[(long)row * 512 + j] : glim[(long)row * 256 + (j - 512)];
}

// ---------------- pointer logits -> out[b,k,s] ----------------
__global__ __launch_bounds__(256) void pointer_kernel(
    const float* __restrict__ gW3, const float* __restrict__ encW4T,
    const float* __restrict__ bias2, const float* __restrict__ V2,
    float* __restrict__ out)
{
  __shared__ float dv[H_], vd[H_];
  const int bid = blockIdx.x;                // k*B + b
  const int b = bid & 63, k = bid >> 6;
  const int t = threadIdx.x;
  dv[t] = gW3[(long)bid * H_ + t] + bias2[t];
  vd[t] = V2[t];
  __syncthreads();
  const float* ebase = encW4T + (long)b * H_ * S_;
  float a0 = 0.f, a1 = 0.f;
#pragma unroll 4
  for (int h = 0; h < H_; ++h) {
    const float d = dv[h], w = vd[h];
    const float* r = ebase + (long)h * S_;
    a0 += tanh_fast(d + r[t]) * w;
    a1 += tanh_fast(d + r[t + 256]) * w;
  }
  const long ro = ((long)b * K_ + k) * S_;
  out[ro + t] = a0;
  out[ro + 256 + t] = a1;
}

// ---------------- host ----------------
extern "C" void kernel_launch(void* const* d_in, const int* in_sizes, int n_in,
                              void* d_out, int out_size, void* d_ws, size_t ws_size,
                              hipStream_t stream)
{
  const int*   users = (const int*)d_in[0];
  const int*   cand  = (const int*)d_in[1];
  const int*   tidx  = (const int*)d_in[2];
  const float* eu    = (const float*)d_in[3];
  const float* ei    = (const float*)d_in[4];
  const float* Wq    = (const float*)d_in[5];
  const float* bq    = (const float*)d_in[6];
  const float* Wk    = (const float*)d_in[7];
  const float* bk    = (const float*)d_in[8];
  const float* Wv    = (const float*)d_in[9];
  const float* bv    = (const float*)d_in[10];
  const float* Wo    = (const float*)d_in[11];
  const float* bo    = (const float*)d_in[12];
  const float* ln1g  = (const float*)d_in[13];
  const float* ln1b  = (const float*)d_in[14];
  const float* Wf1   = (const float*)d_in[15];
  const float* bf1   = (const float*)d_in[16];
  const float* Wf2   = (const float*)d_in[17];
  const float* bf2   = (const float*)d_in[18];
  const float* ln2g  = (const float*)d_in[19];
  const float* ln2b  = (const float*)d_in[20];
  const float* W_ih  = (const float*)d_in[21];
  const float* W_hh  = (const float*)d_in[22];
  const float* b_ih  = (const float*)d_in[23];
  const float* b_hh  = (const float*)d_in[24];
  const float* W_D1  = (const float*)d_in[25];
  const float* W_D2  = (const float*)d_in[26];
  const float* bias1 = (const float*)d_in[27];
  const float* V_D1  = (const float*)d_in[28];
  const float* W_D3  = (const float*)d_in[29];
  const float* W_D4  = (const float*)d_in[30];
  const float* bias2 = (const float*)d_in[31];
  const float* V_D2  = (const float*)d_in[32];

  float* ws = (float*)d_ws;
  const long XSZ  = (long)B_ * S_ * H_;        // 8388608 floats
  float* x    = ws;                            // enc lives here at the end
  float* qb   = x  + XSZ;                      // q / Wo-out / encW2 / encW4T
  float* kb   = qb + XSZ;                      // k / FFN mid / encW4
  float* vb   = kb + XSZ;                      // v / small arena
  float* ao   = vb + XSZ;                      // attn out / encW2T
  float* attc = ao + XSZ;                      // att chunk / FFN y2 chunk
  // small arena (inside vb, used after attention phase)
  float* inp    = vb;                          // 262144
  float* Xp     = inp  + 262144;               // 1048576
  float* WhhT   = Xp   + 1048576;              // 262144
  float* dec    = WhhT + 262144;               // 524288
  float* decW1  = dec  + 524288;               // 262144
  float* glim   = decW1 + 262144;              // 262144
  float* gcat   = glim + 262144;               // 786432
  float* gcatW3 = gcat + 786432;               // 262144

  float* out = (float*)d_out;

  // 1. gather x
  gather_x<<<dim3(32768), dim3(256), 0, stream>>>(users, cand, eu, ei, x);

  // 2. q,k,v projections
  gemm_kernel<false,false><<<dim3(2,256), dim3(256), 0, stream>>>(x, Wq, bq, qb, 32768, H_, H_, H_, H_, H_, 0,0,0);
  gemm_kernel<false,false><<<dim3(2,256), dim3(256), 0, stream>>>(x, Wk, bk, kb, 32768, H_, H_, H_, H_, H_, 0,0,0);
  gemm_kernel<false,false><<<dim3(2,256), dim3(256), 0, stream>>>(x, Wv, bv, vb, 32768, H_, H_, H_, H_, H_, 0,0,0);

  // 3. attention, 4 chunks of 16 batches
  for (int c = 0; c < 4; ++c) {
    const long qoff = (long)c * 16 * S_ * H_;
    gemm_kernel<true,false><<<dim3(4,4,16), dim3(256), 0, stream>>>(
        qb + qoff, kb + qoff, nullptr, attc, S_, S_, H_, H_, H_, S_,
        (long)S_*H_, (long)S_*H_, (long)S_*S_);
    attn_softmax<<<dim3(16*S_), dim3(256), 0, stream>>>(attc);
    gemm_kernel<false,false><<<dim3(2,4,16), dim3(256), 0, stream>>>(
        attc, vb + qoff, nullptr, ao + qoff, S_, H_, S_, S_, H_, H_,
        (long)S_*S_, (long)S_*H_, (long)S_*H_);
  }

  // 4. Wo projection + residual LN1 (y into qb region)
  gemm_kernel<false,false><<<dim3(2,256), dim3(256), 0, stream>>>(ao, Wo, bo, qb, 32768, H_, H_, H_, H_, H_, 0,0,0);
  ln_res<<<dim3(32768), dim3(256), 0, stream>>>(x, qb, ln1g, ln1b);

  // 5. FFN, 4 chunks of 8192 rows (mid in kb, y2 in attc)
  for (int c = 0; c < 4; ++c) {
    float* xc = x + (long)c * 8192 * H_;
    gemm_kernel<false,true ><<<dim3(8,64), dim3(256), 0, stream>>>(xc, Wf1, bf1, kb, 8192, H4_, H_, H_, H4_, H4_, 0,0,0);
    gemm_kernel<false,false><<<dim3(2,64), dim3(256), 0, stream>>>(kb, Wf2, bf2, attc, 8192, H_, H4_, H4_, H_, H_, 0,0,0);
    ln_res<<<dim3(8192), dim3(256), 0, stream>>>(xc, attc, ln2g, ln2b);
  }
  // x now holds enc

  // 6. enc @ W_D2 -> qb, enc @ W_D4 -> kb; transpose to (b,h,s)
  gemm_kernel<false,false><<<dim3(2,256), dim3(256), 0, stream>>>(x, W_D2, nullptr, qb, 32768, H_, H_, H_, H_, H_, 0,0,0);
  gemm_kernel<false,false><<<dim3(2,256), dim3(256), 0, stream>>>(x, W_D4, nullptr, kb, 32768, H_, H_, H_, H_, H_, 0,0,0);
  transpose_bsh<<<dim3(16,8,64), dim3(256), 0, stream>>>(qb, ao);   // encW2T -> ao
  transpose_bsh<<<dim3(16,8,64), dim3(256), 0, stream>>>(kb, qb);   // encW4T -> qb

  // 7. LSTM
  gather_inputs<<<dim3(1024), dim3(256), 0, stream>>>(tidx, x, inp);
  gemm_kernel<true,false><<<dim3(8,8), dim3(256), 0, stream>>>(inp, W_ih, b_ih, Xp, K_*B_, H4_, H_, H_, H_, H4_, 0,0,0);
  transpose_whh<<<dim3(1024), dim3(256), 0, stream>>>(W_hh, WhhT);
  lstm_all<<<dim3(B_), dim3(1024), 0, stream>>>(Xp, WhhT, b_hh, dec);

  // 8. glimpse
  gemm_kernel<false,false><<<dim3(2,8), dim3(256), 0, stream>>>(dec, W_D1, nullptr, decW1, K_*B_, H_, 2*H_, 2*H_, H_, H_, 0,0,0);
  glimpse_kernel<<<dim3(K_*B_), dim3(256), 0, stream>>>(decW1, ao, x, bias1, V_D1, glim);

  // 9. pointer
  concat_gcat<<<dim3(3072), dim3(256), 0, stream>>>(dec, glim, gcat);
  gemm_kernel<false,false><<<dim3(2,8), dim3(256), 0, stream>>>(gcat, W_D3, nullptr, gcatW3, K_*B_, H_, 3*H_, 3*H_, H_, H_, 0,0,0);
  pointer_kernel<<<dim3(K_*B_), dim3(256), 0, stream>>>(gcatW3, qb, bias2, V_D2, out);
}

// Round 6
// 1186.497 us; speedup vs baseline: 2.0316x; 2.0216x over previous
//
#include <hip/hip_runtime.h>
#include <hip/hip_bf16.h>
#include <math.h>

#define B_   64
#define S_   512
#define K_   16
#define H_   256
#define H4_  1024

typedef __attribute__((ext_vector_type(4))) float f32x4;
typedef __attribute__((ext_vector_type(8))) short bf16x8;

// ---------------- helpers ----------------
__device__ __forceinline__ float wave_reduce_sum(float v) {
#pragma unroll
  for (int off = 32; off; off >>= 1) v += __shfl_down(v, off, 64);
  return v;
}
__device__ __forceinline__ float wave_reduce_max(float v) {
#pragma unroll
  for (int off = 32; off; off >>= 1) v = fmaxf(v, __shfl_down(v, off, 64));
  return v;
}
__device__ __forceinline__ float tanh_fast(float x) {
  const float e = __expf(2.f * x);
  return 1.f - __fdividef(2.f, e + 1.f);
}
__device__ __forceinline__ float sigmoid_fast(float x) {
  return __fdividef(1.f, 1.f + __expf(-x));
}
__device__ __forceinline__ ushort f2bf(float f) {   // RNE fp32->bf16
  union { float f; unsigned u; } v; v.f = f;
  unsigned r = v.u + 0x7FFFu + ((v.u >> 16) & 1u);
  return (ushort)(r >> 16);
}

// ---------------- gather: x = [embed_item[cand], embed_user[user]] (fp32 + bf16) ----------------
__global__ void gather_x(const int* __restrict__ users, const int* __restrict__ cand,
                         const float* __restrict__ eu, const float* __restrict__ ei,
                         float* __restrict__ x, ushort* __restrict__ xb)
{
  int idx = blockIdx.x * 256 + threadIdx.x;          // B*S*H = 8388608
  int h  = idx & (H_ - 1);
  int bs = idx >> 8;
  int b  = bs >> 9;
  float v;
  if (h < 192) v = ei[(long)cand[bs] * 192 + h];
  else         v = eu[(long)users[b] * 64 + (h - 192)];
  x[idx] = v;
  xb[idx] = f2bf(v);
}

// ---------------- transpose+convert weights: in fp32 [R,C] -> out bf16 [C,R] ----------------
__global__ __launch_bounds__(256) void tcvt(const float* __restrict__ in, ushort* __restrict__ out,
                                            int R, int C)
{
  __shared__ float t[32][33];
  const int c0 = blockIdx.x * 32, r0 = blockIdx.y * 32;
  const int tx = threadIdx.x & 31, ty = threadIdx.x >> 5;   // ty 0..7
#pragma unroll
  for (int i = 0; i < 4; ++i)
    t[ty + 8 * i][tx] = in[(long)(r0 + ty + 8 * i) * C + c0 + tx];
  __syncthreads();
#pragma unroll
  for (int i = 0; i < 4; ++i)
    out[(long)(c0 + ty + 8 * i) * R + r0 + tx] = f2bf(t[tx][ty + 8 * i]);
}

// ---------------- flat fp32 -> bf16 ----------------
__global__ void cvtflat(const float* __restrict__ in, ushort* __restrict__ out)
{
  int idx = blockIdx.x * 256 + threadIdx.x;
  out[idx] = f2bf(in[idx]);
}

// ---------------- bf16 MFMA GEMM: C = A[M,K] @ BT[N,K]^T (+bias)(+relu) ----------------
// 128x128 tile, BK=32, 4 waves (2x2), wave = 64x64 = 4x4 mfma_f32_16x16x32_bf16 frags.
// Staging: 2 threads/row, each stages 32 BYTES (2 x uint4 = 16 ushorts) -> full 64B row.
// OM: 0 = fp32 out, 1 = bf16 out, 2 = fp32 batched-T out [b][h=N][s] (S=512,H=256),
//     3 = bf16 batched-T out (same layout). OM 2/3 require bz==0, rows = b*512+s.
template<int OM, bool RELU>
__global__ __launch_bounds__(256) void gemm_bf16(
    const ushort* __restrict__ A, const ushort* __restrict__ BT,
    const float* __restrict__ bias, void* __restrict__ Cv,
    int K, int ldA, int ldB, int ldC, long sA, long sB, long sC)
{
  __shared__ ushort Al[128][40];   // pad 32->40 elems (80B rows)
  __shared__ ushort Bl[128][40];
  const int bx = blockIdx.x, by = blockIdx.y, bz = blockIdx.z;
  A  += (long)bz * sA + (long)by * 128 * ldA;
  BT += (long)bz * sB + (long)bx * 128 * ldB;
  const int tid = threadIdx.x, lane = tid & 63, wave = tid >> 6;
  const int wr = wave >> 1, wc = wave & 1;
  const int fr = lane & 15, fq = lane >> 4;
  const int srow = tid & 127;
  const int scol = (tid >> 7) * 16;               // ushort offset: 0 or 16

  const f32x4 fzero = {0.f, 0.f, 0.f, 0.f};
  f32x4 acc[4][4];
#pragma unroll
  for (int i = 0; i < 4; ++i)
#pragma unroll
    for (int j = 0; j < 4; ++j) acc[i][j] = fzero;

  for (int k0 = 0; k0 < K; k0 += 32) {
    const ushort* ap = A  + (long)srow * ldA + k0 + scol;
    const ushort* bp = BT + (long)srow * ldB + k0 + scol;
    *(uint4*)&Al[srow][scol]     = *(const uint4*)(ap);
    *(uint4*)&Al[srow][scol + 8] = *(const uint4*)(ap + 8);
    *(uint4*)&Bl[srow][scol]     = *(const uint4*)(bp);
    *(uint4*)&Bl[srow][scol + 8] = *(const uint4*)(bp + 8);
    __syncthreads();
    bf16x8 af[4], bfr[4];
#pragma unroll
    for (int i = 0; i < 4; ++i) af[i]  = *(const bf16x8*)&Al[wr * 64 + i * 16 + fr][fq * 8];
#pragma unroll
    for (int j = 0; j < 4; ++j) bfr[j] = *(const bf16x8*)&Bl[wc * 64 + j * 16 + fr][fq * 8];
#pragma unroll
    for (int i = 0; i < 4; ++i)
#pragma unroll
      for (int j = 0; j < 4; ++j)
        acc[i][j] = __builtin_amdgcn_mfma_f32_16x16x32_bf16(af[i], bfr[j], acc[i][j], 0, 0, 0);
    __syncthreads();
  }

  const int rowb = by * 128 + wr * 64 + fq * 4;
  const int colb = bx * 128 + wc * 64 + fr;
#pragma unroll
  for (int j = 0; j < 4; ++j) {
    const int colg = colb + j * 16;
    const float bb = bias ? bias[colg] : 0.f;
#pragma unroll
    for (int i = 0; i < 4; ++i) {
      const int rowg = rowb + i * 16;
      if (OM == 0) {
        float* C = (float*)Cv;
#pragma unroll
        for (int r = 0; r < 4; ++r) {
          float o = acc[i][j][r] + bb;
          if (RELU) o = fmaxf(o, 0.f);
          C[(long)bz * sC + (long)(rowg + r) * ldC + colg] = o;
        }
      } else if (OM == 1) {
        ushort* C = (ushort*)Cv;
#pragma unroll
        for (int r = 0; r < 4; ++r) {
          float o = acc[i][j][r] + bb;
          if (RELU) o = fmaxf(o, 0.f);
          C[(long)bz * sC + (long)(rowg + r) * ldC + colg] = f2bf(o);
        }
      } else if (OM == 2) {
        float* C = (float*)Cv;
        const long ct = ((long)(rowg >> 9) * H_ + colg) * S_ + (rowg & 511);
        float4 o;
        o.x = acc[i][j][0] + bb; o.y = acc[i][j][1] + bb;
        o.z = acc[i][j][2] + bb; o.w = acc[i][j][3] + bb;
        *(float4*)&C[ct] = o;
      } else {
        ushort* C = (ushort*)Cv;
        const long ct = ((long)(rowg >> 9) * H_ + colg) * S_ + (rowg & 511);
        ushort4 o;
        o.x = f2bf(acc[i][j][0] + bb); o.y = f2bf(acc[i][j][1] + bb);
        o.z = f2bf(acc[i][j][2] + bb); o.w = f2bf(acc[i][j][3] + bb);
        *(ushort4*)&C[ct] = o;
      }
    }
  }
}

// ---------------- attention softmax: fp32 scores -> bf16 probs ----------------
__global__ __launch_bounds__(256) void attn_softmax(const float* __restrict__ att,
                                                    ushort* __restrict__ attb)
{
  __shared__ float red[4];
  const long row = blockIdx.x;
  const float* p = att + row * S_;
  const int t = threadIdx.x, lane = t & 63, wid = t >> 6;
  float v0 = p[t] * 0.0625f, v1 = p[t + 256] * 0.0625f;
  float m = wave_reduce_max(fmaxf(v0, v1));
  if (!lane) red[wid] = m;
  __syncthreads();
  const float bm = fmaxf(fmaxf(red[0], red[1]), fmaxf(red[2], red[3]));
  const float e0 = __expf(v0 - bm), e1 = __expf(v1 - bm);
  float s = wave_reduce_sum(e0 + e1);
  __syncthreads();
  if (!lane) red[wid] = s;
  __syncthreads();
  const float inv = __fdividef(1.f, red[0] + red[1] + red[2] + red[3]);
  ushort* q = attb + row * S_;
  q[t] = f2bf(e0 * inv); q[t + 256] = f2bf(e1 * inv);
}

// ---------------- residual + layernorm -> x (fp32) and xb (bf16) ----------------
__global__ __launch_bounds__(256) void ln_res(float* __restrict__ x, const float* __restrict__ y,
                                              const float* __restrict__ g, const float* __restrict__ b,
                                              ushort* __restrict__ xb)
{
  __shared__ float red[4];
  const long row = blockIdx.x;
  const int t = threadIdx.x, lane = t & 63, wid = t >> 6;
  float v = x[row * H_ + t] + y[row * H_ + t];
  float s = wave_reduce_sum(v);
  if (!lane) red[wid] = s;
  __syncthreads();
  const float mean = (red[0] + red[1] + red[2] + red[3]) * (1.f / H_);
  const float d = v - mean;
  float s2 = wave_reduce_sum(d * d);
  __syncthreads();
  if (!lane) red[wid] = s2;
  __syncthreads();
  const float var = (red[0] + red[1] + red[2] + red[3]) * (1.f / H_);
  const float o = d * rsqrtf(var + 1e-5f) * g[t] + b[t];
  x[row * H_ + t] = o;
  xb[row * H_ + t] = f2bf(o);
}

// ---------------- gather LSTM inputs from encb (bf16), step 0 zeroed ----------------
__global__ void gather_inputs(const int* __restrict__ tidx, const ushort* __restrict__ encb,
                              ushort* __restrict__ inpb)
{
  int idx = blockIdx.x * 256 + threadIdx.x;          // 1024*256
  int h = idx & 255, kb = idx >> 8;
  int b = kb & 63, k = kb >> 6;
  ushort v = 0;
  if (k > 0) {
    int s = tidx[b * K_ + k];
    v = encb[((long)b * S_ + s) * H_ + h];
  }
  inpb[idx] = v;
}

// ---------------- transpose W_hh (4H x H) -> (H x 4H) fp32 ----------------
__global__ void transpose_whh(const float* __restrict__ W, float* __restrict__ WT)
{
  int idx = blockIdx.x * 256 + threadIdx.x;          // 262144
  int r = idx >> 8, d = idx & 255;
  WT[d * H4_ + r] = W[idx];
}

// ---------------- fused LSTM: one block per batch row, all 16 steps ----------------
__global__ __launch_bounds__(1024) void lstm_all(const float* __restrict__ Xp,
                                                 const float* __restrict__ WhhT,
                                                 const float* __restrict__ b_hh,
                                                 float* __restrict__ dec)
{
  __shared__ float hs[H_];
  __shared__ float gates[H4_];
  const int b = blockIdx.x, j = threadIdx.x;
  float c = 0.f;
  if (j < H_) hs[j] = 0.f;
  const float bh = b_hh[j];
  __syncthreads();
  for (int step = 0; step < K_; ++step) {
    float acc = Xp[((long)step * B_ + b) * H4_ + j] + bh;
#pragma unroll 8
    for (int d = 0; d < H_; ++d)
      acc += hs[d] * WhhT[d * H4_ + j];
    gates[j] = acc;
    __syncthreads();
    if (j < H_) {
      const float gi = gates[j], gf = gates[256 + j], gg = gates[512 + j], go = gates[768 + j];
      c = sigmoid_fast(gf) * c + sigmoid_fast(gi) * tanh_fast(gg);
      const float h = sigmoid_fast(go) * tanh_fast(c);
      hs[j] = h;
      const long rw = ((long)step * B_ + b) * (2 * H_);
      dec[rw + j] = h;
      dec[rw + H_ + j] = c;
    }
    __syncthreads();
  }
}

// ---------------- glimpse: per-lane-s scores, softmax, weighted sum ----------------
__global__ __launch_bounds__(256) void glimpse_kernel(
    const float* __restrict__ decW1, const float* __restrict__ encW2T,
    const float* __restrict__ enc, const float* __restrict__ bias1,
    const float* __restrict__ V1, float* __restrict__ glim)
{
  __shared__ float dv[H_], vd[H_], sc[S_], red[4];
  const int bid = blockIdx.x;                // k*B + b
  const int b = bid & 63;
  const int t = threadIdx.x, lane = t & 63, wv = t >> 6;
  dv[t] = decW1[(long)bid * H_ + t] + bias1[t];
  vd[t] = V1[t];
  __syncthreads();
  const float* ebase = encW2T + (long)b * H_ * S_;
  float a0 = 0.f, a1 = 0.f;
#pragma unroll 4
  for (int h = 0; h < H_; ++h) {
    const float d = dv[h], w = vd[h];
    const float* r = ebase + (long)h * S_;
    a0 += tanh_fast(d + r[t]) * w;
    a1 += tanh_fast(d + r[t + 256]) * w;
  }
  float m = wave_reduce_max(fmaxf(a0, a1));
  if (!lane) red[wv] = m;
  __syncthreads();
  const float bm = fmaxf(fmaxf(red[0], red[1]), fmaxf(red[2], red[3]));
  const float e0 = __expf(a0 - bm), e1 = __expf(a1 - bm);
  float ssum = wave_reduce_sum(e0 + e1);
  __syncthreads();
  if (!lane) red[wv] = ssum;
  __syncthreads();
  const float inv = __fdividef(1.f, red[0] + red[1] + red[2] + red[3]);
  sc[t] = e0 * inv; sc[t + 256] = e1 * inv;
  __syncthreads();
  float acc = 0.f;
  const float* eb = enc + (long)b * S_ * H_ + t;
#pragma unroll 4
  for (int s = 0; s < S_; ++s) acc += sc[s] * eb[(long)s * H_];
  glim[(long)bid * H_ + t] = acc;
}

// ---------------- gcat = [dec | glim] -> bf16 ----------------
__global__ void concat_gcat(const float* __restrict__ dec, const float* __restrict__ glim,
                            ushort* __restrict__ gcatb)
{
  int idx = blockIdx.x * 256 + threadIdx.x;   // 1024*768
  int j = idx % 768, row = idx / 768;
  float v = (j < 512) ? dec[(long)row * 512 + j] : glim[(long)row * 256 + (j - 512)];
  gcatb[idx] = f2bf(v);
}

// ---------------- pointer logits -> out[b,k,s] ----------------
__global__ __launch_bounds__(256) void pointer_kernel(
    const float* __restrict__ gW3, const float* __restrict__ encW4T,
    const float* __restrict__ bias2, const float* __restrict__ V2,
    float* __restrict__ out)
{
  __shared__ float dv[H_], vd[H_];
  const int bid = blockIdx.x;                // k*B + b
  const int b = bid & 63, k = bid >> 6;
  const int t = threadIdx.x;
  dv[t] = gW3[(long)bid * H_ + t] + bias2[t];
  vd[t] = V2[t];
  __syncthreads();
  const float* ebase = encW4T + (long)b * H_ * S_;
  float a0 = 0.f, a1 = 0.f;
#pragma unroll 4
  for (int h = 0; h < H_; ++h) {
    const float d = dv[h], w = vd[h];
    const float* r = ebase + (long)h * S_;
    a0 += tanh_fast(d + r[t]) * w;
    a1 += tanh_fast(d + r[t + 256]) * w;
  }
  const long ro = ((long)b * K_ + k) * S_;
  out[ro + t] = a0;
  out[ro + 256 + t] = a1;
}

// ---------------- host ----------------
extern "C" void kernel_launch(void* const* d_in, const int* in_sizes, int n_in,
                              void* d_out, int out_size, void* d_ws, size_t ws_size,
                              hipStream_t stream)
{
  const int*   users = (const int*)d_in[0];
  const int*   cand  = (const int*)d_in[1];
  const int*   tidx  = (const int*)d_in[2];
  const float* eu    = (const float*)d_in[3];
  const float* ei    = (const float*)d_in[4];
  const float* Wq    = (const float*)d_in[5];
  const float* bq    = (const float*)d_in[6];
  const float* Wk    = (const float*)d_in[7];
  const float* bk    = (const float*)d_in[8];
  const float* Wv    = (const float*)d_in[9];
  const float* bv    = (const float*)d_in[10];
  const float* Wo    = (const float*)d_in[11];
  const float* bo    = (const float*)d_in[12];
  const float* ln1g  = (const float*)d_in[13];
  const float* ln1b  = (const float*)d_in[14];
  const float* Wf1   = (const float*)d_in[15];
  const float* bf1   = (const float*)d_in[16];
  const float* Wf2   = (const float*)d_in[17];
  const float* bf2   = (const float*)d_in[18];
  const float* ln2g  = (const float*)d_in[19];
  const float* ln2b  = (const float*)d_in[20];
  const float* W_ih  = (const float*)d_in[21];
  const float* W_hh  = (const float*)d_in[22];
  const float* b_ih  = (const float*)d_in[23];
  const float* b_hh  = (const float*)d_in[24];
  const float* W_D1  = (const float*)d_in[25];
  const float* W_D2  = (const float*)d_in[26];
  const float* bias1 = (const float*)d_in[27];
  const float* V_D1  = (const float*)d_in[28];
  const float* W_D3  = (const float*)d_in[29];
  const float* W_D4  = (const float*)d_in[30];
  const float* bias2 = (const float*)d_in[31];
  const float* V_D2  = (const float*)d_in[32];

  float* ws = (float*)d_ws;
  // arena (float-element offsets)
  float*  x      = ws;                               // fp32 8388608 (x -> enc)
  ushort* xb     = (ushort*)(ws + 8388608);          // bf16 (xb -> encb)
  ushort* qb     = (ushort*)(ws + 12582912);
  ushort* kb     = (ushort*)(ws + 16777216);
  ushort* vTb    = (ushort*)(ws + 20971520);         // [b][h][s] bf16
  ushort* aob    = (ushort*)(ws + 25165824);
  ushort* attb   = (ushort*)(ws + 29360128);         // 16x512x512 bf16 chunk
  float*  ych    = ws + 31457280;                    // 8192x256 fp32 chunk
  ushort* wts    = (ushort*)(ws + 33554432);         // bf16 weights arena
  float*  att    = ws + 34603008;                    // 16x512x512 fp32 chunk
  ushort* midb   = (ushort*)att;                     // alias: FFN phase (att dead)
  float*  sm     = ws + 38797312;                    // small arena
  float*  encW2T = ws + 12582912;                    // overlays qb+kb (dead)
  float*  encW4T = ws + 20971520;                    // overlays vTb+aob (dead)

  ushort* WqT  = wts;
  ushort* WkT  = WqT  + 65536;
  ushort* WvT  = WkT  + 65536;
  ushort* WoT  = WvT  + 65536;
  ushort* Wf1T = WoT  + 65536;
  ushort* Wf2T = Wf1T + 262144;
  ushort* WD1T = Wf2T + 262144;
  ushort* WD2T = WD1T + 131072;
  ushort* WD3T = WD2T + 65536;
  ushort* WD4T = WD3T + 196608;
  ushort* Wihb = WD4T + 65536;

  ushort* inpb   = (ushort*)sm;                      // 1024x256 bf16
  float*  Xp     = sm + 131072;                      // 1024x1024 fp32
  float*  WhhT   = sm + 1179648;
  float*  dec    = sm + 1441792;                     // 16x64x512 fp32
  ushort* decb   = (ushort*)(sm + 1966080);
  float*  decW1  = sm + 2228224;
  float*  glim   = sm + 2490368;
  ushort* gcatb  = (ushort*)(sm + 2752512);          // 1024x768 bf16
  float*  gcatW3 = sm + 3145728;

  float* out = (float*)d_out;
  const long SH = (long)S_ * H_;                     // 131072

  // 0. weight prep (transpose + cvt to bf16 [N,K])
  tcvt<<<dim3(8,8),   dim3(256), 0, stream>>>(Wq,   WqT,  256, 256);
  tcvt<<<dim3(8,8),   dim3(256), 0, stream>>>(Wk,   WkT,  256, 256);
  tcvt<<<dim3(8,8),   dim3(256), 0, stream>>>(Wv,   WvT,  256, 256);
  tcvt<<<dim3(8,8),   dim3(256), 0, stream>>>(Wo,   WoT,  256, 256);
  tcvt<<<dim3(32,8),  dim3(256), 0, stream>>>(Wf1,  Wf1T, 256, 1024);
  tcvt<<<dim3(8,32),  dim3(256), 0, stream>>>(Wf2,  Wf2T, 1024, 256);
  tcvt<<<dim3(8,16),  dim3(256), 0, stream>>>(W_D1, WD1T, 512, 256);
  tcvt<<<dim3(8,8),   dim3(256), 0, stream>>>(W_D2, WD2T, 256, 256);
  tcvt<<<dim3(8,24),  dim3(256), 0, stream>>>(W_D3, WD3T, 768, 256);
  tcvt<<<dim3(8,8),   dim3(256), 0, stream>>>(W_D4, WD4T, 256, 256);
  cvtflat<<<dim3(1024), dim3(256), 0, stream>>>(W_ih, Wihb);   // already [N,K]

  // 1. gather
  gather_x<<<dim3(32768), dim3(256), 0, stream>>>(users, cand, eu, ei, x, xb);

  // 2. q,k (bf16 out), v (bf16 transposed out)
  gemm_bf16<1,false><<<dim3(2,256), dim3(256), 0, stream>>>(xb, WqT, bq, qb,  256, 256, 256, 256, 0,0,0);
  gemm_bf16<1,false><<<dim3(2,256), dim3(256), 0, stream>>>(xb, WkT, bk, kb,  256, 256, 256, 256, 0,0,0);
  gemm_bf16<3,false><<<dim3(2,256), dim3(256), 0, stream>>>(xb, WvT, bv, vTb, 256, 256, 256, 0,   0,0,0);

  // 3. attention: 4 chunks of 16 batches
  for (int c = 0; c < 4; ++c) {
    const long qo = (long)c * 16 * SH;
    gemm_bf16<0,false><<<dim3(4,4,16), dim3(256), 0, stream>>>(
        qb + qo, kb + qo, nullptr, att, 256, 256, 256, 512, SH, SH, (long)S_*S_);
    attn_softmax<<<dim3(16*S_), dim3(256), 0, stream>>>(att, attb);
    gemm_bf16<1,false><<<dim3(2,4,16), dim3(256), 0, stream>>>(
        attb, vTb + qo, nullptr, aob + qo, 512, 512, 512, 256, (long)S_*S_, SH, SH);
  }

  // 4. Wo + LN1, 4 row-chunks of 8192
  for (int c = 0; c < 4; ++c) {
    const long off = (long)c * 8192 * H_;
    gemm_bf16<0,false><<<dim3(2,64), dim3(256), 0, stream>>>(aob + off, WoT, bo, ych, 256, 256, 256, 256, 0,0,0);
    ln_res<<<dim3(8192), dim3(256), 0, stream>>>(x + off, ych, ln1g, ln1b, xb + off);
  }

  // 5. FFN, 4 row-chunks of 8192 (mid bf16 in att slot)
  for (int c = 0; c < 4; ++c) {
    const long off = (long)c * 8192 * H_;
    gemm_bf16<1,true ><<<dim3(8,64), dim3(256), 0, stream>>>(xb + off, Wf1T, bf1, midb, 256, 256, 256, 1024, 0,0,0);
    gemm_bf16<0,false><<<dim3(2,64), dim3(256), 0, stream>>>(midb, Wf2T, bf2, ych, 1024, 1024, 1024, 256, 0,0,0);
    ln_res<<<dim3(8192), dim3(256), 0, stream>>>(x + off, ych, ln2g, ln2b, xb + off);
  }
  // x = enc (fp32), xb = encb (bf16)

  // 6. enc projections, emitted pre-transposed [b][h][s] fp32
  gemm_bf16<2,false><<<dim3(2,256), dim3(256), 0, stream>>>(xb, WD2T, nullptr, encW2T, 256, 256, 256, 0, 0,0,0);
  gemm_bf16<2,false><<<dim3(2,256), dim3(256), 0, stream>>>(xb, WD4T, nullptr, encW4T, 256, 256, 256, 0, 0,0,0);

  // 7. LSTM
  gather_inputs<<<dim3(1024), dim3(256), 0, stream>>>(tidx, xb, inpb);
  gemm_bf16<0,false><<<dim3(8,8), dim3(256), 0, stream>>>(inpb, Wihb, b_ih, Xp, 256, 256, 256, 1024, 0,0,0);
  transpose_whh<<<dim3(1024), dim3(256), 0, stream>>>(W_hh, WhhT);
  lstm_all<<<dim3(B_), dim3(1024), 0, stream>>>(Xp, WhhT, b_hh, dec);

  // 8. glimpse
  cvtflat<<<dim3(2048), dim3(256), 0, stream>>>(dec, decb);
  gemm_bf16<0,false><<<dim3(2,8), dim3(256), 0, stream>>>(decb, WD1T, nullptr, decW1, 512, 512, 512, 256, 0,0,0);
  glimpse_kernel<<<dim3(K_*B_), dim3(256), 0, stream>>>(decW1, encW2T, x, bias1, V_D1, glim);

  // 9. pointer
  concat_gcat<<<dim3(3072), dim3(256), 0, stream>>>(dec, glim, gcatb);
  gemm_bf16<0,false><<<dim3(2,8), dim3(256), 0, stream>>>(gcatb, WD3T, nullptr, gcatW3, 768, 768, 768, 256, 0,0,0);
  pointer_kernel<<<dim3(K_*B_), dim3(256), 0, stream>>>(gcatW3, encW4T, bias2, V_D2, out);
}